// Round 2
// baseline (672.759 us; speedup 1.0000x reference)
//
#include <hip/hip_runtime.h>
#include <math.h>

// Problem constants
#define NB   16
#define CC   256
#define NPTS 16384       // 16*32*32
#define KK   8192
#define Z_OUT 4194304    // NPTS*CC
// d_out: [0,Z_OUT) z_q_out (BCHW), [Z_OUT,Z_OUT+NPTS) idx as float, [Z_OUT+NPTS] loss
// d_out scratch reuse timeline:
//   before k_phase1 done: zb16 = bf16[16384][256] at slot 0, ebf = bf16[8192][256] at slot 2,097,152
//   after  k_phase1:      z_t  = f32 [16384][256] over the whole [0, Z_OUT) region (k_tr_z)
//   k_gather finally overwrites [0, Z_OUT) with z_q BCHW.

// ws layout (floats)
#define WS_ZNORM 64
#define WS_ENORM 16448
#define WS_CCNT  24640                // int[16384] candidate counts
#define WS_CIDX  41024                // int[16384][64] candidate k lists
#define CAND_CAP 64
#define MARGIN   4.0e-4f              // > 2*eps_bf16 + d-quantum + enorm spread

typedef short v8s __attribute__((ext_vector_type(8)));
typedef float v4f __attribute__((ext_vector_type(4)));

__device__ __forceinline__ void gl_lds16(const void* g, void* l) {
    __builtin_amdgcn_global_load_lds((const __attribute__((address_space(1))) void*)g,
                                     (__attribute__((address_space(3))) void*)l, 16, 0, 0);
}
__device__ __forceinline__ unsigned short f2bf(float f) {   // RNE, finite inputs
    unsigned int u = __float_as_uint(f);
    return (unsigned short)((u + 0x7FFFu + ((u >> 16) & 1u)) >> 16);
}
// monotone float<->uint encoding for atomicMax on floats of any sign
__device__ __forceinline__ unsigned fenc(float f) {
    unsigned u = __float_as_uint(f);
    return (u & 0x80000000u) ? ~u : (u | 0x80000000u);
}
__device__ __forceinline__ float fdec(unsigned m) {
    unsigned u = (m & 0x80000000u) ? (m & 0x7fffffffu) : ~m;
    return __uint_as_float(u);
}

// ---------------- P0: z BCHW fp32 -> zb16[n][c] bf16 (transpose+cast) ----------------
__global__ void k_prep_z(const float* __restrict__ z, unsigned short* __restrict__ zb16) {
    __shared__ float ts[64][65];
    const int hw0 = blockIdx.x * 64, c0 = blockIdx.y * 64, b = blockIdx.z;
    const int tid = threadIdx.x;
#pragma unroll
    for (int p = 0; p < 4; ++p) {
        int u = p * 256 + tid;
        int ci = u >> 4, j4 = (u & 15) << 2;
        float4 v = *(const float4*)(z + (size_t)b * 262144 + (size_t)(c0 + ci) * 1024 + hw0 + j4);
        ts[ci][j4 + 0] = v.x; ts[ci][j4 + 1] = v.y; ts[ci][j4 + 2] = v.z; ts[ci][j4 + 3] = v.w;
    }
    __syncthreads();
#pragma unroll
    for (int p = 0; p < 4; ++p) {
        int u = p * 256 + tid;
        int hj = u >> 4, i4 = (u & 15) << 2;
        ushort4 o = make_ushort4(f2bf(ts[i4 + 0][hj]), f2bf(ts[i4 + 1][hj]),
                                 f2bf(ts[i4 + 2][hj]), f2bf(ts[i4 + 3][hj]));
        *(ushort4*)(zb16 + (size_t)(b * 1024 + hw0 + hj) * 256 + c0 + i4) = o;
    }
}

// ---------------- P0b: z BCHW fp32 -> z_t[n][c] fp32 (transpose, runs after phase1) --
__global__ void k_tr_z(const float* __restrict__ z, float* __restrict__ zt) {
    __shared__ float ts[64][65];
    const int hw0 = blockIdx.x * 64, c0 = blockIdx.y * 64, b = blockIdx.z;
    const int tid = threadIdx.x;
#pragma unroll
    for (int p = 0; p < 4; ++p) {
        int u = p * 256 + tid;
        int ci = u >> 4, j4 = (u & 15) << 2;
        float4 v = *(const float4*)(z + (size_t)b * 262144 + (size_t)(c0 + ci) * 1024 + hw0 + j4);
        ts[ci][j4 + 0] = v.x; ts[ci][j4 + 1] = v.y; ts[ci][j4 + 2] = v.z; ts[ci][j4 + 3] = v.w;
    }
    __syncthreads();
#pragma unroll
    for (int p = 0; p < 4; ++p) {
        int u = p * 256 + tid;
        int hj = u >> 4, i4 = (u & 15) << 2;
        float4 o = make_float4(ts[i4 + 0][hj], ts[i4 + 1][hj], ts[i4 + 2][hj], ts[i4 + 3][hj]);
        *(float4*)(zt + (size_t)(b * 1024 + hw0 + hj) * 256 + c0 + i4) = o;
    }
}

// ---------------- P1: emb fp32 -> ebf[k][c] bf16 ----------------
__global__ void k_prep_e(const float* __restrict__ emb, unsigned short* __restrict__ ebf) {
    const int i = (blockIdx.x * 256 + threadIdx.x) * 8;
    float4 a = *(const float4*)(emb + i);
    float4 b = *(const float4*)(emb + i + 4);
    *(ushort4*)(ebf + i)     = make_ushort4(f2bf(a.x), f2bf(a.y), f2bf(a.z), f2bf(a.w));
    *(ushort4*)(ebf + i + 4) = make_ushort4(f2bf(b.x), f2bf(b.y), f2bf(b.z), f2bf(b.w));
}

// ---------------- znorm + zero loss ----------------
__global__ void k_znorm(const float* __restrict__ z, float* __restrict__ znorm,
                        float* __restrict__ lossAcc) {
    const int n  = blockIdx.x * 256 + threadIdx.x;
    const int b  = n >> 10, hw = n & 1023;
    const float* p = z + (size_t)b * 262144 + hw;
    float s = 0.0f;
#pragma unroll 8
    for (int c = 0; c < CC; ++c) {
        float v = p[(size_t)c * 1024];
        s = fmaf(v, v, s);
    }
    znorm[n] = s;
    if (n == 0) lossAcc[0] = 0.0f;
}

// ---------------- enorm ----------------
__global__ void k_enorm(const float* __restrict__ emb, float* __restrict__ enorm) {
    const int w = threadIdx.x >> 6, lane = threadIdx.x & 63;
    const int k = blockIdx.x * 4 + w;
    float4 v = *(const float4*)(emb + (size_t)k * CC + lane * 4);
    float s = v.x * v.x + v.y * v.y + v.z * v.z + v.w * v.w;
    for (int off = 32; off > 0; off >>= 1) s += __shfl_down(s, off);
    if (lane == 0) enorm[k] = s;
}

// ---------------- Phase 1: bf16 MFMA dot + online max + candidate collection ----------
// 256 blocks x 512 thr (8 waves). Block = 64 n (B-tile staged ONCE in LDS, 32 KB),
// wave w owns k in [w*1024,(w+1)*1024): 16 s-iters of 64 k, full c=256 per s.
// A (e-rows, L2-resident) loaded straight to registers, ping-pong prefetched.
// NO barriers in the k-loop: runmax merged via LDS atomicMax (ordered-uint floats);
// one __syncthreads after s=0 so the first push sees the global 512-k max (same
// guarantee as the old barrier-synced first round). Staleness later only lowers the
// threshold -> extra candidates -> still exact (rescore fallback unchanged).
// mfma_f32_16x16x32_bf16: A[m=lane&15][c=(lane>>4)*8+j]; B[c][n=lane&15];
// D: col(n)=lane&15, row(k)=(lane>>4)*4+reg.
__global__ __launch_bounds__(512, 6)
void k_phase1(const unsigned short* __restrict__ zb16, const unsigned short* __restrict__ ebf,
              int* __restrict__ candCnt, int* __restrict__ candI) {
    __shared__ short    Bs[8][4][512];      // 32 KB  [cchunk][ntile][lane*8]
    __shared__ unsigned runmaxU[64];        // ordered-uint encoded running max per n
    __shared__ int      cnt[64];
    __shared__ int      lst[64][CAND_CAP];  // 16 KB

    const int tid  = threadIdx.x;
    const int lane = tid & 63;
    const int w    = tid >> 6;
    const int nb   = blockIdx.x << 6;
    const int m16  = lane & 15, q = lane >> 4;

    if (tid < 64) { runmaxU[tid] = 0x007FFFFFu; /* fenc(-inf) */ cnt[tid] = 0; }

    // stage B-tile once: 32 (cc,nt) fragments x 64 lanes x 16B
#pragma unroll
    for (int p = 0; p < 4; ++p) {
        const int g8 = p * 8 + w;          // 0..31, wave-uniform
        const int cc = g8 >> 2, nt = g8 & 3;
        const unsigned short* g = zb16 + (size_t)(nb + nt * 16 + m16) * 256 + cc * 32 + q * 8;
        gl_lds16(g, &Bs[cc][nt][lane * 8]);
    }

    auto loadA = [&](v8s (&a)[4], int kbr, int cc) {
#pragma unroll
        for (int kt = 0; kt < 4; ++kt)
            a[kt] = *(const v8s*)(ebf + (size_t)(kbr + (kt << 4) + m16) * 256 + (cc << 5) + q * 8);
    };

    v8s aP[4], aN[4];
    int kb = w << 10;
    loadA(aP, kb, 0);       // registers only; safe before the staging barrier

    __syncthreads();        // B-tile + cnt/runmax init visible

    v4f acc[16];
#pragma unroll 1
    for (int s = 0; s < 16; ++s) {
        const int kb2 = (s < 15) ? kb + 64 : kb;   // last-iter prefetch clamp
#pragma unroll
        for (int i = 0; i < 16; ++i) acc[i] = (v4f){0.f, 0.f, 0.f, 0.f};

#pragma unroll
        for (int cc = 0; cc < 8; ++cc) {
            v8s bfg[4];
#pragma unroll
            for (int nt = 0; nt < 4; ++nt) bfg[nt] = *(const v8s*)&Bs[cc][nt][lane * 8];
            if ((cc & 1) == 0) {
                loadA(aN, kb, cc + 1);             // prefetch next c-chunk
#pragma unroll
                for (int kt = 0; kt < 4; ++kt)
#pragma unroll
                    for (int nt = 0; nt < 4; ++nt)
                        acc[kt * 4 + nt] = __builtin_amdgcn_mfma_f32_16x16x32_bf16(
                            aP[kt], bfg[nt], acc[kt * 4 + nt], 0, 0, 0);
            } else {
                if (cc < 7) loadA(aP, kb, cc + 1);
                else        loadA(aP, kb2, 0);     // prefetch next s
#pragma unroll
                for (int kt = 0; kt < 4; ++kt)
#pragma unroll
                    for (int nt = 0; nt < 4; ++nt)
                        acc[kt * 4 + nt] = __builtin_amdgcn_mfma_f32_16x16x32_bf16(
                            aN[kt], bfg[nt], acc[kt * 4 + nt], 0, 0, 0);
            }
        }

        // running max update (lock-free across waves)
#pragma unroll
        for (int nt = 0; nt < 4; ++nt) {
            float m = acc[nt][0];
#pragma unroll
            for (int kt = 0; kt < 4; ++kt)
#pragma unroll
                for (int r = 0; r < 4; ++r) m = fmaxf(m, acc[kt * 4 + nt][r]);
            m = fmaxf(m, __shfl_xor(m, 16));
            m = fmaxf(m, __shfl_xor(m, 32));
            if (lane < 16) atomicMax(&runmaxU[nt * 16 + lane], fenc(m));
        }
        if (s == 0) __syncthreads();   // first push sees global 512-k max

        // candidate push
#pragma unroll
        for (int nt = 0; nt < 4; ++nt) {
            const int nl = nt * 16 + m16;
            const float thr = fdec(runmaxU[nl]) - MARGIN;
#pragma unroll
            for (int kt = 0; kt < 4; ++kt)
#pragma unroll
                for (int r = 0; r < 4; ++r) {
                    if (acc[kt * 4 + nt][r] >= thr) {
                        int k = kb + (kt << 4) + q * 4 + r;
                        int pos = atomicAdd(&cnt[nl], 1);
                        if (pos < CAND_CAP) lst[nl][pos] = k;
                    }
                }
        }
        kb += 64;
    }

    __syncthreads();
    if (tid < 64) {
        const int n = nb + tid;
        const int c = cnt[tid];
        candCnt[n] = c;
        const int m = c < CAND_CAP ? c : CAND_CAP;
        for (int i = 0; i < m; ++i) candI[(size_t)n * CAND_CAP + i] = lst[tid][i];
    }
}

// ---------------- Phase 2: exact fp32 rescore, wave-per-n, lane-parallel dot ----------
// One wave owns one n. Lane l holds z_t[n][4l..4l+3] (coalesced 1 KB row load).
// Per candidate: coalesced emb-row load, 4 fmaf + 6-step butterfly -> uniform dot.
// d chain matches prior kernel: d = (zn + enorm[k]) - (p + p); ties -> smallest k.
__global__ __launch_bounds__(256)
void k_rescore2(const float* __restrict__ zt, const float* __restrict__ emb,
                const float* __restrict__ znorm, const float* __restrict__ enorm,
                const int* __restrict__ candCnt, const int* __restrict__ candI,
                float* __restrict__ idx_out) {
    const int lane = threadIdx.x & 63;
    const int n    = blockIdx.x * 4 + (threadIdx.x >> 6);
    const float zn = znorm[n];
    const int  cnt = candCnt[n];
    const float4 zv = *(const float4*)(zt + (size_t)n * CC + lane * 4);
    float bd = __builtin_inff();
    int   bk = 0x7fffffff;
    if (cnt <= CAND_CAP) {
#pragma unroll 1
        for (int i = 0; i < cnt; ++i) {
            const int k = candI[(size_t)n * CAND_CAP + i];
            const float4 ev = *(const float4*)(emb + (size_t)k * CC + lane * 4);
            float p = zv.x * ev.x;
            p = fmaf(zv.y, ev.y, p);
            p = fmaf(zv.z, ev.z, p);
            p = fmaf(zv.w, ev.w, p);
#pragma unroll
            for (int off = 1; off < 64; off <<= 1) p += __shfl_xor(p, off);
            const float d = (zn + enorm[k]) - (p + p);
            if (d < bd || (d == bd && k < bk)) { bd = d; bk = k; }
        }
    } else {
        // overflow fallback: exact full scan, all lanes active, ascending k keeps min-k
#pragma unroll 1
        for (int k = 0; k < KK; ++k) {
            const float4 ev = *(const float4*)(emb + (size_t)k * CC + lane * 4);
            float p = zv.x * ev.x;
            p = fmaf(zv.y, ev.y, p);
            p = fmaf(zv.z, ev.z, p);
            p = fmaf(zv.w, ev.w, p);
#pragma unroll
            for (int off = 1; off < 64; off <<= 1) p += __shfl_xor(p, off);
            const float d = (zn + enorm[k]) - (p + p);
            if (d < bd) { bd = d; bk = k; }
        }
    }
    if (lane == 0) idx_out[n] = (float)bk;
}

// ---------------- gather z_q (BCHW) + loss partials ----------------
__global__ void k_gather(const float* __restrict__ z, const float* __restrict__ emb,
                         const float* __restrict__ idxf, float* __restrict__ out,
                         float* __restrict__ lossAcc) {
    __shared__ float red[256];
    const int bid = blockIdx.x;
    const int b = bid >> 5, h = bid & 31;
    const int t = threadIdx.x;
    const int w_ = t & 31, cg = t >> 5;
    const int n = b * 1024 + h * 32 + w_;
    const int ki = (int)idxf[n];
    const float* ep = emb + (size_t)ki * CC;
    const size_t base = (size_t)b * 262144 + h * 32 + w_;
    float ls = 0.0f;
#pragma unroll 4
    for (int c = cg; c < CC; c += 8) {
        float e = ep[c];
        size_t a = base + (size_t)c * 1024;
        float zv = z[a];
        out[a] = e;
        float df = e - zv;
        ls = fmaf(df, df, ls);
    }
    red[t] = ls;
    __syncthreads();
    for (int s = 128; s > 0; s >>= 1) {
        if (t < s) red[t] += red[t + s];
        __syncthreads();
    }
    if (t == 0) atomicAdd(lossAcc, red[0]);
}

// ---------------- finalize loss ----------------
__global__ void k_loss(const float* __restrict__ lossAcc, float* __restrict__ outLoss) {
    if (threadIdx.x == 0) {
        float m = lossAcc[0] * (1.0f / 4194304.0f);
        outLoss[0] = m + 0.25f * m;
    }
}

extern "C" void kernel_launch(void* const* d_in, const int* in_sizes, int n_in,
                              void* d_out, int out_size, void* d_ws, size_t ws_size,
                              hipStream_t stream) {
    const float* z   = (const float*)d_in[0];
    const float* emb = (const float*)d_in[1];
    float* outf = (float*)d_out;
    float* wsf  = (float*)d_ws;

    float* lossAcc = wsf;
    float* znorm   = wsf + WS_ZNORM;
    float* enorm   = wsf + WS_ENORM;
    int*   candCnt = (int*)(wsf + WS_CCNT);
    int*   candI   = (int*)(wsf + WS_CIDX);

    // d_out z_q region doubles as scratch: bf16 zb16/ebf until k_phase1 completes,
    // then fp32 z_t until k_gather overwrites it with z_q.
    unsigned short* zb16 = (unsigned short*)outf;                  // 8 MB
    unsigned short* ebf  = (unsigned short*)(outf + 2097152);      // 4 MB
    float* zt = outf;                                              // 16 MB (after phase1)

    k_prep_z<<<dim3(16, 4, 16), 256, 0, stream>>>(z, zb16);
    k_prep_e<<<1024, 256, 0, stream>>>(emb, ebf);
    k_znorm<<<64, 256, 0, stream>>>(z, znorm, lossAcc);
    k_enorm<<<2048, 256, 0, stream>>>(emb, enorm);
    k_phase1<<<256, 512, 0, stream>>>(zb16, ebf, candCnt, candI);
    k_tr_z<<<dim3(16, 4, 16), 256, 0, stream>>>(z, zt);
    k_rescore2<<<4096, 256, 0, stream>>>(zt, emb, znorm, enorm, candCnt, candI, outf + Z_OUT);
    k_gather<<<512, 256, 0, stream>>>(z, emb, outf + Z_OUT, outf, lossAcc);
    k_loss<<<1, 64, 0, stream>>>(lossAcc, outf + Z_OUT + NPTS);
}

// Round 3
// 502.770 us; speedup vs baseline: 1.3381x; 1.3381x over previous
//
#include <hip/hip_runtime.h>
#include <math.h>

// Problem constants
#define NB   16
#define CC   256
#define NPTS 16384       // 16*32*32
#define KK   8192
#define Z_OUT 4194304    // NPTS*CC
// d_out: [0,Z_OUT) z_q_out (BCHW), [Z_OUT,Z_OUT+NPTS) idx as float, [Z_OUT+NPTS] loss
// d_out scratch reuse timeline:
//   before k_push done: zb16 = bf16[16384][256] at slot 0, ebf = bf16[8192][256] at
//     slot 2,097,152, runmaxG = uint[16384] at slot 3,145,728
//   after  k_push:      z_t  = f32 [16384][256] over [0, Z_OUT) (k_tr_z)
//   k_gather finally overwrites [0, Z_OUT) with z_q BCHW.

// ws layout (floats)
#define WS_ZNORM 64
#define WS_ENORM 16448
#define WS_CCNT  24640                // int[16384] candidate counts
#define WS_CIDX  41024                // int[16384][64] candidate k lists
#define CAND_CAP 64
#define MARGIN   4.0e-4f              // > 2*eps_bf16 + d-quantum + enorm spread

typedef short v8s __attribute__((ext_vector_type(8)));
typedef float v4f __attribute__((ext_vector_type(4)));

__device__ __forceinline__ void gl_lds16(const void* g, void* l) {
    __builtin_amdgcn_global_load_lds((const __attribute__((address_space(1))) void*)g,
                                     (__attribute__((address_space(3))) void*)l, 16, 0, 0);
}
__device__ __forceinline__ unsigned short f2bf(float f) {   // RNE, finite inputs
    unsigned int u = __float_as_uint(f);
    return (unsigned short)((u + 0x7FFFu + ((u >> 16) & 1u)) >> 16);
}
// monotone float<->uint encoding for atomicMax on floats of any sign
__device__ __forceinline__ unsigned fenc(float f) {
    unsigned u = __float_as_uint(f);
    return (u & 0x80000000u) ? ~u : (u | 0x80000000u);
}
__device__ __forceinline__ float fdec(unsigned m) {
    unsigned u = (m & 0x80000000u) ? (m & 0x7fffffffu) : ~m;
    return __uint_as_float(u);
}

// ---------------- P0: z BCHW fp32 -> zb16[n][c] bf16 (transpose+cast) ----------------
__global__ void k_prep_z(const float* __restrict__ z, unsigned short* __restrict__ zb16) {
    __shared__ float ts[64][65];
    const int hw0 = blockIdx.x * 64, c0 = blockIdx.y * 64, b = blockIdx.z;
    const int tid = threadIdx.x;
#pragma unroll
    for (int p = 0; p < 4; ++p) {
        int u = p * 256 + tid;
        int ci = u >> 4, j4 = (u & 15) << 2;
        float4 v = *(const float4*)(z + (size_t)b * 262144 + (size_t)(c0 + ci) * 1024 + hw0 + j4);
        ts[ci][j4 + 0] = v.x; ts[ci][j4 + 1] = v.y; ts[ci][j4 + 2] = v.z; ts[ci][j4 + 3] = v.w;
    }
    __syncthreads();
#pragma unroll
    for (int p = 0; p < 4; ++p) {
        int u = p * 256 + tid;
        int hj = u >> 4, i4 = (u & 15) << 2;
        ushort4 o = make_ushort4(f2bf(ts[i4 + 0][hj]), f2bf(ts[i4 + 1][hj]),
                                 f2bf(ts[i4 + 2][hj]), f2bf(ts[i4 + 3][hj]));
        *(ushort4*)(zb16 + (size_t)(b * 1024 + hw0 + hj) * 256 + c0 + i4) = o;
    }
}

// ---------------- P0b: z BCHW fp32 -> z_t[n][c] fp32 (transpose, runs after phase1) --
__global__ void k_tr_z(const float* __restrict__ z, float* __restrict__ zt) {
    __shared__ float ts[64][65];
    const int hw0 = blockIdx.x * 64, c0 = blockIdx.y * 64, b = blockIdx.z;
    const int tid = threadIdx.x;
#pragma unroll
    for (int p = 0; p < 4; ++p) {
        int u = p * 256 + tid;
        int ci = u >> 4, j4 = (u & 15) << 2;
        float4 v = *(const float4*)(z + (size_t)b * 262144 + (size_t)(c0 + ci) * 1024 + hw0 + j4);
        ts[ci][j4 + 0] = v.x; ts[ci][j4 + 1] = v.y; ts[ci][j4 + 2] = v.z; ts[ci][j4 + 3] = v.w;
    }
    __syncthreads();
#pragma unroll
    for (int p = 0; p < 4; ++p) {
        int u = p * 256 + tid;
        int hj = u >> 4, i4 = (u & 15) << 2;
        float4 o = make_float4(ts[i4 + 0][hj], ts[i4 + 1][hj], ts[i4 + 2][hj], ts[i4 + 3][hj]);
        *(float4*)(zt + (size_t)(b * 1024 + hw0 + hj) * 256 + c0 + i4) = o;
    }
}

// ---------------- P1: emb fp32 -> ebf[k][c] bf16 ----------------
__global__ void k_prep_e(const float* __restrict__ emb, unsigned short* __restrict__ ebf) {
    const int i = (blockIdx.x * 256 + threadIdx.x) * 8;
    float4 a = *(const float4*)(emb + i);
    float4 b = *(const float4*)(emb + i + 4);
    *(ushort4*)(ebf + i)     = make_ushort4(f2bf(a.x), f2bf(a.y), f2bf(a.z), f2bf(a.w));
    *(ushort4*)(ebf + i + 4) = make_ushort4(f2bf(b.x), f2bf(b.y), f2bf(b.z), f2bf(b.w));
}

// ---------------- znorm + zero loss + init runmax/candCnt ----------------
__global__ void k_znorm(const float* __restrict__ z, float* __restrict__ znorm,
                        float* __restrict__ lossAcc, unsigned* __restrict__ runmaxG,
                        int* __restrict__ candCnt) {
    const int n  = blockIdx.x * 256 + threadIdx.x;
    const int b  = n >> 10, hw = n & 1023;
    const float* p = z + (size_t)b * 262144 + hw;
    float s = 0.0f;
#pragma unroll 8
    for (int c = 0; c < CC; ++c) {
        float v = p[(size_t)c * 1024];
        s = fmaf(v, v, s);
    }
    znorm[n] = s;
    runmaxG[n] = 0x007FFFFFu;   // fenc(-inf)
    candCnt[n] = 0;
    if (n == 0) lossAcc[0] = 0.0f;
}

// ---------------- enorm ----------------
__global__ void k_enorm(const float* __restrict__ emb, float* __restrict__ enorm) {
    const int w = threadIdx.x >> 6, lane = threadIdx.x & 63;
    const int k = blockIdx.x * 4 + w;
    float4 v = *(const float4*)(emb + (size_t)k * CC + lane * 4);
    float s = v.x * v.x + v.y * v.y + v.z * v.z + v.w * v.w;
    for (int off = 32; off > 0; off >>= 1) s += __shfl_down(s, off);
    if (lane == 0) enorm[k] = s;
}

// ---------------- Phase 1a: per-n max of bf16 dot (MFMA, barrier-free k-loop) --------
// Grid (4,256): blockIdx.x = k-quarter, blockIdx.y = 64-n tile. 256 thr = 4 waves.
// Block stages its 64n x 256c z-tile in LDS ONCE (32 KB). Wave w owns k in
// [kq*2048 + w*512, +512): 8 s-chunks of 64 k; A (e-rows, L2-resident) loaded
// straight to registers. Per-lane register running max; merge at end via LDS +
// one global atomicMax per n. ZERO barriers/atomics in the k-loop.
// mfma_f32_16x16x32_bf16: A[m=lane&15][c=(lane>>4)*8+j]; B[c][n=lane&15];
// D: col(n)=lane&15, row(k)=(lane>>4)*4+reg.
__global__ __launch_bounds__(256, 4)
void k_max(const unsigned short* __restrict__ zb16, const unsigned short* __restrict__ ebf,
           unsigned* __restrict__ runmaxG) {
    __shared__ short Bs[8][4][512];      // 32 KB  [cchunk][ntile][lane*8]
    __shared__ float wavemax[4][64];

    const int tid  = threadIdx.x;
    const int lane = tid & 63;
    const int w    = tid >> 6;
    const int kq   = blockIdx.x;
    const int nb   = blockIdx.y << 6;
    const int m16  = lane & 15, q = lane >> 4;

    // stage B-tile once: 32 (cc,nt) fragments x 64 lanes x 16B
#pragma unroll
    for (int p = 0; p < 8; ++p) {
        const int g8 = p * 4 + w;          // 0..31, wave-uniform
        const int cc = g8 >> 2, nt = g8 & 3;
        const unsigned short* g = zb16 + (size_t)(nb + nt * 16 + m16) * 256 + cc * 32 + q * 8;
        gl_lds16(g, &Bs[cc][nt][lane * 8]);
    }
    __syncthreads();

    float rm0 = -__builtin_inff(), rm1 = -__builtin_inff();
    float rm2 = -__builtin_inff(), rm3 = -__builtin_inff();

    int kb = (kq << 11) + (w << 9);
#pragma unroll 1
    for (int s = 0; s < 8; ++s) {
        v4f acc[16];
#pragma unroll
        for (int i = 0; i < 16; ++i) acc[i] = (v4f){0.f, 0.f, 0.f, 0.f};
#pragma unroll
        for (int cc = 0; cc < 8; ++cc) {
            v8s a[4], bfg[4];
#pragma unroll
            for (int kt = 0; kt < 4; ++kt)
                a[kt] = *(const v8s*)(ebf + (size_t)(kb + (kt << 4) + m16) * 256 + (cc << 5) + q * 8);
#pragma unroll
            for (int nt = 0; nt < 4; ++nt) bfg[nt] = *(const v8s*)&Bs[cc][nt][lane * 8];
#pragma unroll
            for (int kt = 0; kt < 4; ++kt)
#pragma unroll
                for (int nt = 0; nt < 4; ++nt)
                    acc[kt * 4 + nt] = __builtin_amdgcn_mfma_f32_16x16x32_bf16(
                        a[kt], bfg[nt], acc[kt * 4 + nt], 0, 0, 0);
        }
#pragma unroll
        for (int kt = 0; kt < 4; ++kt)
#pragma unroll
            for (int r = 0; r < 4; ++r) {
                rm0 = fmaxf(rm0, acc[kt * 4 + 0][r]);
                rm1 = fmaxf(rm1, acc[kt * 4 + 1][r]);
                rm2 = fmaxf(rm2, acc[kt * 4 + 2][r]);
                rm3 = fmaxf(rm3, acc[kt * 4 + 3][r]);
            }
        kb += 64;
    }

    float rm[4] = {rm0, rm1, rm2, rm3};
#pragma unroll
    for (int nt = 0; nt < 4; ++nt) {
        float m = rm[nt];
        m = fmaxf(m, __shfl_xor(m, 16));
        m = fmaxf(m, __shfl_xor(m, 32));
        if (lane < 16) wavemax[w][nt * 16 + lane] = m;
    }
    __syncthreads();
    if (tid < 64) {
        float r = wavemax[0][tid];
        r = fmaxf(r, wavemax[1][tid]);
        r = fmaxf(r, wavemax[2][tid]);
        r = fmaxf(r, wavemax[3][tid]);
        atomicMax(&runmaxG[nb + tid], fenc(r));
    }
}

// ---------------- Phase 1b: recompute dots, push candidates vs FINAL threshold -------
// Same sweep as k_max. Threshold per n is the final global max (k_max done at kernel
// boundary) minus MARGIN -> candidate counts deterministic and minimal. Pushes go
// straight to global candI via device atomicAdd on candCnt. ZERO barriers in k-loop.
__global__ __launch_bounds__(256, 4)
void k_push(const unsigned short* __restrict__ zb16, const unsigned short* __restrict__ ebf,
            const unsigned* __restrict__ runmaxG, int* __restrict__ candCnt,
            int* __restrict__ candI) {
    __shared__ short Bs[8][4][512];      // 32 KB

    const int tid  = threadIdx.x;
    const int lane = tid & 63;
    const int w    = tid >> 6;
    const int kq   = blockIdx.x;
    const int nb   = blockIdx.y << 6;
    const int m16  = lane & 15, q = lane >> 4;

#pragma unroll
    for (int p = 0; p < 8; ++p) {
        const int g8 = p * 4 + w;
        const int cc = g8 >> 2, nt = g8 & 3;
        const unsigned short* g = zb16 + (size_t)(nb + nt * 16 + m16) * 256 + cc * 32 + q * 8;
        gl_lds16(g, &Bs[cc][nt][lane * 8]);
    }

    // final thresholds for this lane's 4 n-columns (registers, loop-invariant)
    float thr[4];
#pragma unroll
    for (int nt = 0; nt < 4; ++nt)
        thr[nt] = fdec(runmaxG[nb + nt * 16 + m16]) - MARGIN;

    __syncthreads();

    int kb = (kq << 11) + (w << 9);
#pragma unroll 1
    for (int s = 0; s < 8; ++s) {
        v4f acc[16];
#pragma unroll
        for (int i = 0; i < 16; ++i) acc[i] = (v4f){0.f, 0.f, 0.f, 0.f};
#pragma unroll
        for (int cc = 0; cc < 8; ++cc) {
            v8s a[4], bfg[4];
#pragma unroll
            for (int kt = 0; kt < 4; ++kt)
                a[kt] = *(const v8s*)(ebf + (size_t)(kb + (kt << 4) + m16) * 256 + (cc << 5) + q * 8);
#pragma unroll
            for (int nt = 0; nt < 4; ++nt) bfg[nt] = *(const v8s*)&Bs[cc][nt][lane * 8];
#pragma unroll
            for (int kt = 0; kt < 4; ++kt)
#pragma unroll
                for (int nt = 0; nt < 4; ++nt)
                    acc[kt * 4 + nt] = __builtin_amdgcn_mfma_f32_16x16x32_bf16(
                        a[kt], bfg[nt], acc[kt * 4 + nt], 0, 0, 0);
        }
#pragma unroll
        for (int nt = 0; nt < 4; ++nt) {
            const int n = nb + nt * 16 + m16;
#pragma unroll
            for (int kt = 0; kt < 4; ++kt)
#pragma unroll
                for (int r = 0; r < 4; ++r) {
                    if (acc[kt * 4 + nt][r] >= thr[nt]) {
                        int k = kb + (kt << 4) + q * 4 + r;
                        int pos = atomicAdd(&candCnt[n], 1);
                        if (pos < CAND_CAP) candI[(size_t)n * CAND_CAP + pos] = k;
                    }
                }
        }
        kb += 64;
    }
}

// ---------------- Phase 2: exact fp32 rescore, wave-per-n, lane-parallel dot ----------
// One wave owns one n. Lane l holds z_t[n][4l..4l+3] (coalesced 1 KB row load).
// Per candidate: coalesced emb-row load, 4 fmaf + 6-step butterfly -> uniform dot.
// d = (zn + enorm[k]) - (p + p); ties -> smallest k (order-invariant selection).
__global__ __launch_bounds__(256)
void k_rescore2(const float* __restrict__ zt, const float* __restrict__ emb,
                const float* __restrict__ znorm, const float* __restrict__ enorm,
                const int* __restrict__ candCnt, const int* __restrict__ candI,
                float* __restrict__ idx_out) {
    const int lane = threadIdx.x & 63;
    const int n    = blockIdx.x * 4 + (threadIdx.x >> 6);
    const float zn = znorm[n];
    const int  cnt = candCnt[n];
    const float4 zv = *(const float4*)(zt + (size_t)n * CC + lane * 4);
    float bd = __builtin_inff();
    int   bk = 0x7fffffff;
    if (cnt <= CAND_CAP) {
#pragma unroll 1
        for (int i = 0; i < cnt; ++i) {
            const int k = candI[(size_t)n * CAND_CAP + i];
            const float4 ev = *(const float4*)(emb + (size_t)k * CC + lane * 4);
            float p = zv.x * ev.x;
            p = fmaf(zv.y, ev.y, p);
            p = fmaf(zv.z, ev.z, p);
            p = fmaf(zv.w, ev.w, p);
#pragma unroll
            for (int off = 1; off < 64; off <<= 1) p += __shfl_xor(p, off);
            const float d = (zn + enorm[k]) - (p + p);
            if (d < bd || (d == bd && k < bk)) { bd = d; bk = k; }
        }
    } else {
        // overflow fallback: exact full scan, all lanes active, ascending k keeps min-k
#pragma unroll 1
        for (int k = 0; k < KK; ++k) {
            const float4 ev = *(const float4*)(emb + (size_t)k * CC + lane * 4);
            float p = zv.x * ev.x;
            p = fmaf(zv.y, ev.y, p);
            p = fmaf(zv.z, ev.z, p);
            p = fmaf(zv.w, ev.w, p);
#pragma unroll
            for (int off = 1; off < 64; off <<= 1) p += __shfl_xor(p, off);
            const float d = (zn + enorm[k]) - (p + p);
            if (d < bd) { bd = d; bk = k; }
        }
    }
    if (lane == 0) idx_out[n] = (float)bk;
}

// ---------------- gather z_q (BCHW) + loss partials ----------------
__global__ void k_gather(const float* __restrict__ z, const float* __restrict__ emb,
                         const float* __restrict__ idxf, float* __restrict__ out,
                         float* __restrict__ lossAcc) {
    __shared__ float red[256];
    const int bid = blockIdx.x;
    const int b = bid >> 5, h = bid & 31;
    const int t = threadIdx.x;
    const int w_ = t & 31, cg = t >> 5;
    const int n = b * 1024 + h * 32 + w_;
    const int ki = (int)idxf[n];
    const float* ep = emb + (size_t)ki * CC;
    const size_t base = (size_t)b * 262144 + h * 32 + w_;
    float ls = 0.0f;
#pragma unroll 4
    for (int c = cg; c < CC; c += 8) {
        float e = ep[c];
        size_t a = base + (size_t)c * 1024;
        float zv = z[a];
        out[a] = e;
        float df = e - zv;
        ls = fmaf(df, df, ls);
    }
    red[t] = ls;
    __syncthreads();
    for (int s = 128; s > 0; s >>= 1) {
        if (t < s) red[t] += red[t + s];
        __syncthreads();
    }
    if (t == 0) atomicAdd(lossAcc, red[0]);
}

// ---------------- finalize loss ----------------
__global__ void k_loss(const float* __restrict__ lossAcc, float* __restrict__ outLoss) {
    if (threadIdx.x == 0) {
        float m = lossAcc[0] * (1.0f / 4194304.0f);
        outLoss[0] = m + 0.25f * m;
    }
}

extern "C" void kernel_launch(void* const* d_in, const int* in_sizes, int n_in,
                              void* d_out, int out_size, void* d_ws, size_t ws_size,
                              hipStream_t stream) {
    const float* z   = (const float*)d_in[0];
    const float* emb = (const float*)d_in[1];
    float* outf = (float*)d_out;
    float* wsf  = (float*)d_ws;

    float* lossAcc = wsf;
    float* znorm   = wsf + WS_ZNORM;
    float* enorm   = wsf + WS_ENORM;
    int*   candCnt = (int*)(wsf + WS_CCNT);
    int*   candI   = (int*)(wsf + WS_CIDX);

    // d_out z_q region doubles as scratch: bf16 zb16/ebf + runmaxG until k_push
    // completes, then fp32 z_t until k_gather overwrites it with z_q.
    unsigned short* zb16 = (unsigned short*)outf;                  // 8 MB
    unsigned short* ebf  = (unsigned short*)(outf + 2097152);      // 4 MB
    unsigned* runmaxG    = (unsigned*)(outf + 3145728);            // 64 KB
    float* zt = outf;                                              // 16 MB (after push)

    k_prep_z<<<dim3(16, 4, 16), 256, 0, stream>>>(z, zb16);
    k_prep_e<<<1024, 256, 0, stream>>>(emb, ebf);
    k_znorm<<<64, 256, 0, stream>>>(z, znorm, lossAcc, runmaxG, candCnt);
    k_enorm<<<2048, 256, 0, stream>>>(emb, enorm);
    k_max <<<dim3(4, 256), 256, 0, stream>>>(zb16, ebf, runmaxG);
    k_push<<<dim3(4, 256), 256, 0, stream>>>(zb16, ebf, runmaxG, candCnt, candI);
    k_tr_z<<<dim3(16, 4, 16), 256, 0, stream>>>(z, zt);
    k_rescore2<<<4096, 256, 0, stream>>>(zt, emb, znorm, enorm, candCnt, candI, outf + Z_OUT);
    k_gather<<<512, 256, 0, stream>>>(z, emb, outf + Z_OUT, outf, lossAcc);
    k_loss<<<1, 64, 0, stream>>>(lossAcc, outf + Z_OUT + NPTS);
}

// Round 4
// 299.557 us; speedup vs baseline: 2.2459x; 1.6784x over previous
//
#include <hip/hip_runtime.h>
#include <math.h>

// Problem constants
#define NB   16
#define CC   256
#define NPTS 16384       // 16*32*32
#define KK   8192
#define Z_OUT 4194304    // NPTS*CC
// d_out: [0,Z_OUT) z_q_out (BCHW), [Z_OUT,Z_OUT+NPTS) idx as float, [Z_OUT+NPTS] loss
// d_out scratch reuse timeline:
//   before k_cand done: zb16 = bf16[16384][256] at slot 0, ebf = bf16[8192][256] at
//     slot 2,097,152
//   after  k_cand:      z_t  = f32 [16384][256] over [0, Z_OUT) (k_tr_z)
//   k_gather finally overwrites [0, Z_OUT) with z_q BCHW.

// ws layout (floats)
#define WS_ZNORM 64
#define WS_ENORM 16448
#define WS_CCNT  24640                // int[16384] candidate counts
#define WS_CIDX  41024                // int[16384][64] candidate k lists
#define CAND_CAP 64
#define LCAP     96                   // pre-filter per-n LDS list capacity
#define MARGIN   4.0e-4f              // > 2*eps_bf16 + d-quantum + enorm spread

typedef short v8s __attribute__((ext_vector_type(8)));
typedef float v4f __attribute__((ext_vector_type(4)));

__device__ __forceinline__ void gl_lds16(const void* g, void* l) {
    __builtin_amdgcn_global_load_lds((const __attribute__((address_space(1))) void*)g,
                                     (__attribute__((address_space(3))) void*)l, 16, 0, 0);
}
__device__ __forceinline__ unsigned short f2bf(float f) {   // RNE, finite inputs
    unsigned int u = __float_as_uint(f);
    return (unsigned short)((u + 0x7FFFu + ((u >> 16) & 1u)) >> 16);
}
// monotone float<->uint encoding for atomicMax on floats of any sign
__device__ __forceinline__ unsigned fenc(float f) {
    unsigned u = __float_as_uint(f);
    return (u & 0x80000000u) ? ~u : (u | 0x80000000u);
}
__device__ __forceinline__ float fdec(unsigned m) {
    unsigned u = (m & 0x80000000u) ? (m & 0x7fffffffu) : ~m;
    return __uint_as_float(u);
}

// ---------------- P0: z BCHW fp32 -> zb16[n][c] bf16 (transpose+cast) ----------------
__global__ void k_prep_z(const float* __restrict__ z, unsigned short* __restrict__ zb16) {
    __shared__ float ts[64][65];
    const int hw0 = blockIdx.x * 64, c0 = blockIdx.y * 64, b = blockIdx.z;
    const int tid = threadIdx.x;
#pragma unroll
    for (int p = 0; p < 4; ++p) {
        int u = p * 256 + tid;
        int ci = u >> 4, j4 = (u & 15) << 2;
        float4 v = *(const float4*)(z + (size_t)b * 262144 + (size_t)(c0 + ci) * 1024 + hw0 + j4);
        ts[ci][j4 + 0] = v.x; ts[ci][j4 + 1] = v.y; ts[ci][j4 + 2] = v.z; ts[ci][j4 + 3] = v.w;
    }
    __syncthreads();
#pragma unroll
    for (int p = 0; p < 4; ++p) {
        int u = p * 256 + tid;
        int hj = u >> 4, i4 = (u & 15) << 2;
        ushort4 o = make_ushort4(f2bf(ts[i4 + 0][hj]), f2bf(ts[i4 + 1][hj]),
                                 f2bf(ts[i4 + 2][hj]), f2bf(ts[i4 + 3][hj]));
        *(ushort4*)(zb16 + (size_t)(b * 1024 + hw0 + hj) * 256 + c0 + i4) = o;
    }
}

// ---------------- P0b: z BCHW fp32 -> z_t[n][c] fp32 (transpose, runs after k_cand) --
__global__ void k_tr_z(const float* __restrict__ z, float* __restrict__ zt) {
    __shared__ float ts[64][65];
    const int hw0 = blockIdx.x * 64, c0 = blockIdx.y * 64, b = blockIdx.z;
    const int tid = threadIdx.x;
#pragma unroll
    for (int p = 0; p < 4; ++p) {
        int u = p * 256 + tid;
        int ci = u >> 4, j4 = (u & 15) << 2;
        float4 v = *(const float4*)(z + (size_t)b * 262144 + (size_t)(c0 + ci) * 1024 + hw0 + j4);
        ts[ci][j4 + 0] = v.x; ts[ci][j4 + 1] = v.y; ts[ci][j4 + 2] = v.z; ts[ci][j4 + 3] = v.w;
    }
    __syncthreads();
#pragma unroll
    for (int p = 0; p < 4; ++p) {
        int u = p * 256 + tid;
        int hj = u >> 4, i4 = (u & 15) << 2;
        float4 o = make_float4(ts[i4 + 0][hj], ts[i4 + 1][hj], ts[i4 + 2][hj], ts[i4 + 3][hj]);
        *(float4*)(zt + (size_t)(b * 1024 + hw0 + hj) * 256 + c0 + i4) = o;
    }
}

// ---------------- P1: emb fp32 -> ebf[k][c] bf16 ----------------
__global__ void k_prep_e(const float* __restrict__ emb, unsigned short* __restrict__ ebf) {
    const int i = (blockIdx.x * 256 + threadIdx.x) * 8;
    float4 a = *(const float4*)(emb + i);
    float4 b = *(const float4*)(emb + i + 4);
    *(ushort4*)(ebf + i)     = make_ushort4(f2bf(a.x), f2bf(a.y), f2bf(a.z), f2bf(a.w));
    *(ushort4*)(ebf + i + 4) = make_ushort4(f2bf(b.x), f2bf(b.y), f2bf(b.z), f2bf(b.w));
}

// ---------------- znorm + zero loss ----------------
__global__ void k_znorm(const float* __restrict__ z, float* __restrict__ znorm,
                        float* __restrict__ lossAcc) {
    const int n  = blockIdx.x * 256 + threadIdx.x;
    const int b  = n >> 10, hw = n & 1023;
    const float* p = z + (size_t)b * 262144 + hw;
    float s = 0.0f;
#pragma unroll 8
    for (int c = 0; c < CC; ++c) {
        float v = p[(size_t)c * 1024];
        s = fmaf(v, v, s);
    }
    znorm[n] = s;
    if (n == 0) lossAcc[0] = 0.0f;
}

// ---------------- enorm ----------------
__global__ void k_enorm(const float* __restrict__ emb, float* __restrict__ enorm) {
    const int w = threadIdx.x >> 6, lane = threadIdx.x & 63;
    const int k = blockIdx.x * 4 + w;
    float4 v = *(const float4*)(emb + (size_t)k * CC + lane * 4);
    float s = v.x * v.x + v.y * v.y + v.z * v.z + v.w * v.w;
    for (int off = 32; off > 0; off >>= 1) s += __shfl_down(s, off);
    if (lane == 0) enorm[k] = s;
}

// ---------------- Phase 1: single-sweep MFMA candidate generation -------------------
// 256 blocks x 512 thr (8 waves), block = 64 n (B z-tile staged ONCE in LDS, 32 KB),
// wave w owns k in [w*1024,(w+1)*1024): 16 chunks of 64 k, full c=256 per chunk.
// A (e-rows, L2-resident) loaded straight to registers. k-loop is barrier-free except
// a staleness-bounding __syncthreads every 4 chunks.
// Progressive threshold per chunk = max(shared LDS runmax, OWN chunk max in-register)
// - MARGIN: own-chunk term makes the push condition robust to LDS staleness (always a
// superset of the final-margin set). (k, dot) pairs pushed to LDS lists (cap LCAP).
// Epilogue: block covers full k -> runmaxU is the TRUE global bf16 max per n; filter
// stored dots vs finalmax-MARGIN -> candCnt is the exact margin-window count (~2-5).
// Overflow anywhere -> candCnt=KK -> rescore exact full-scan fallback.
// mfma_f32_16x16x32_bf16: A[m=lane&15][c=(lane>>4)*8+j]; B[c][n=lane&15];
// D: col(n)=lane&15, row(k)=(lane>>4)*4+reg.
__global__ __launch_bounds__(512, 2)
void k_cand(const unsigned short* __restrict__ zb16, const unsigned short* __restrict__ ebf,
            int* __restrict__ candCnt, int* __restrict__ candI) {
    __shared__ short    Bs[8][4][512];      // 32 KB  [cchunk][ntile][lane*8]
    __shared__ unsigned runmaxU[64];        // ordered-uint running max per n
    __shared__ int      cnt[64];
    __shared__ int      lstK[64][LCAP];     // 24 KB
    __shared__ float    lstD[64][LCAP];     // 24 KB

    const int tid  = threadIdx.x;
    const int lane = tid & 63;
    const int w    = tid >> 6;
    const int nb   = blockIdx.x << 6;
    const int m16  = lane & 15, q = lane >> 4;

    if (tid < 64) { runmaxU[tid] = 0x007FFFFFu; /* fenc(-inf) */ cnt[tid] = 0; }

    // stage B-tile once: 32 (cc,nt) fragments x 64 lanes x 16B; 4 per wave
#pragma unroll
    for (int p = 0; p < 4; ++p) {
        const int g8 = p * 8 + w;          // 0..31, wave-uniform
        const int cc = g8 >> 2, nt = g8 & 3;
        const unsigned short* g = zb16 + (size_t)(nb + nt * 16 + m16) * 256 + cc * 32 + q * 8;
        gl_lds16(g, &Bs[cc][nt][lane * 8]);
    }
    __syncthreads();       // Bs + runmaxU/cnt init visible (barrier drains vmcnt)

    int kb = w << 10;
#pragma unroll 1
    for (int s = 0; s < 16; ++s) {
        v4f acc[16];
#pragma unroll
        for (int i = 0; i < 16; ++i) acc[i] = (v4f){0.f, 0.f, 0.f, 0.f};

#pragma unroll
        for (int cc = 0; cc < 8; ++cc) {
            v8s a[4], bfg[4];
#pragma unroll
            for (int kt = 0; kt < 4; ++kt)
                a[kt] = *(const v8s*)(ebf + (size_t)(kb + (kt << 4) + m16) * 256 + (cc << 5) + q * 8);
#pragma unroll
            for (int nt = 0; nt < 4; ++nt) bfg[nt] = *(const v8s*)&Bs[cc][nt][lane * 8];
#pragma unroll
            for (int kt = 0; kt < 4; ++kt)
#pragma unroll
                for (int nt = 0; nt < 4; ++nt)
                    acc[kt * 4 + nt] = __builtin_amdgcn_mfma_f32_16x16x32_bf16(
                        a[kt], bfg[nt], acc[kt * 4 + nt], 0, 0, 0);
        }

        // chunk epilogue: own-chunk max per n-column (all lanes end up holding the max
        // for their m16 column), merge into shared runmax, then push with robust thr.
        float mx[4];
#pragma unroll
        for (int nt = 0; nt < 4; ++nt) {
            float m = acc[nt * 1 + 0][0];   // acc[kt*4+nt] -> kt=0 term below anyway
            m = acc[0 * 4 + nt][0];
#pragma unroll
            for (int kt = 0; kt < 4; ++kt)
#pragma unroll
                for (int r = 0; r < 4; ++r) m = fmaxf(m, acc[kt * 4 + nt][r]);
            m = fmaxf(m, __shfl_xor(m, 16));
            m = fmaxf(m, __shfl_xor(m, 32));
            mx[nt] = m;                     // all lanes: chunk max of column n=nt*16+m16
            if (lane < 16) atomicMax(&runmaxU[nt * 16 + lane], fenc(m));
        }
#pragma unroll
        for (int nt = 0; nt < 4; ++nt) {
            const int nl = nt * 16 + m16;
            const float thr = fmaxf(fdec(runmaxU[nl]), mx[nt]) - MARGIN;
#pragma unroll
            for (int kt = 0; kt < 4; ++kt)
#pragma unroll
                for (int r = 0; r < 4; ++r) {
                    if (acc[kt * 4 + nt][r] >= thr) {
                        int k = kb + (kt << 4) + q * 4 + r;
                        int pos = atomicAdd(&cnt[nl], 1);
                        if (pos < LCAP) { lstK[nl][pos] = k; lstD[nl][pos] = acc[kt * 4 + nt][r]; }
                    }
                }
        }
        kb += 64;
        if ((s & 3) == 3 && s < 15) __syncthreads();   // bound cross-wave staleness
    }

    __syncthreads();   // all pushes + atomicMax done; runmaxU now TRUE global max per n
    if (tid < 64) {
        const int n = nb + tid;
        const int c = cnt[tid];
        if (c > LCAP) {
            candCnt[n] = KK;               // overflow -> exact full-scan fallback
        } else {
            const float thr = fdec(runmaxU[tid]) - MARGIN;
            int kept = 0;
            for (int i = 0; i < c; ++i) {
                if (lstD[tid][i] >= thr) {
                    if (kept < CAND_CAP) candI[(size_t)n * CAND_CAP + kept] = lstK[tid][i];
                    ++kept;
                }
            }
            candCnt[n] = (kept > CAND_CAP) ? KK : kept;
        }
    }
}

// ---------------- Phase 2: exact fp32 rescore, wave-per-n, lane-parallel dot ----------
// One wave owns one n. Lane l holds z_t[n][4l..4l+3] (coalesced 1 KB row load).
// Per candidate: coalesced emb-row load, 4 fmaf + 6-step butterfly -> uniform dot.
// d = (zn + enorm[k]) - (p + p); ties -> smallest k (order-invariant selection).
__global__ __launch_bounds__(256)
void k_rescore2(const float* __restrict__ zt, const float* __restrict__ emb,
                const float* __restrict__ znorm, const float* __restrict__ enorm,
                const int* __restrict__ candCnt, const int* __restrict__ candI,
                float* __restrict__ idx_out) {
    const int lane = threadIdx.x & 63;
    const int n    = blockIdx.x * 4 + (threadIdx.x >> 6);
    const float zn = znorm[n];
    const int  cnt = candCnt[n];
    const float4 zv = *(const float4*)(zt + (size_t)n * CC + lane * 4);
    float bd = __builtin_inff();
    int   bk = 0x7fffffff;
    if (cnt <= CAND_CAP) {
#pragma unroll 1
        for (int i = 0; i < cnt; ++i) {
            const int k = candI[(size_t)n * CAND_CAP + i];
            const float4 ev = *(const float4*)(emb + (size_t)k * CC + lane * 4);
            float p = zv.x * ev.x;
            p = fmaf(zv.y, ev.y, p);
            p = fmaf(zv.z, ev.z, p);
            p = fmaf(zv.w, ev.w, p);
#pragma unroll
            for (int off = 1; off < 64; off <<= 1) p += __shfl_xor(p, off);
            const float d = (zn + enorm[k]) - (p + p);
            if (d < bd || (d == bd && k < bk)) { bd = d; bk = k; }
        }
    } else {
        // overflow fallback: exact full scan, all lanes active, ascending k keeps min-k
#pragma unroll 1
        for (int k = 0; k < KK; ++k) {
            const float4 ev = *(const float4*)(emb + (size_t)k * CC + lane * 4);
            float p = zv.x * ev.x;
            p = fmaf(zv.y, ev.y, p);
            p = fmaf(zv.z, ev.z, p);
            p = fmaf(zv.w, ev.w, p);
#pragma unroll
            for (int off = 1; off < 64; off <<= 1) p += __shfl_xor(p, off);
            const float d = (zn + enorm[k]) - (p + p);
            if (d < bd) { bd = d; bk = k; }
        }
    }
    if (lane == 0) idx_out[n] = (float)bk;
}

// ---------------- gather z_q (BCHW) + loss partials ----------------
__global__ void k_gather(const float* __restrict__ z, const float* __restrict__ emb,
                         const float* __restrict__ idxf, float* __restrict__ out,
                         float* __restrict__ lossAcc) {
    __shared__ float red[256];
    const int bid = blockIdx.x;
    const int b = bid >> 5, h = bid & 31;
    const int t = threadIdx.x;
    const int w_ = t & 31, cg = t >> 5;
    const int n = b * 1024 + h * 32 + w_;
    const int ki = (int)idxf[n];
    const float* ep = emb + (size_t)ki * CC;
    const size_t base = (size_t)b * 262144 + h * 32 + w_;
    float ls = 0.0f;
#pragma unroll 4
    for (int c = cg; c < CC; c += 8) {
        float e = ep[c];
        size_t a = base + (size_t)c * 1024;
        float zv = z[a];
        out[a] = e;
        float df = e - zv;
        ls = fmaf(df, df, ls);
    }
    red[t] = ls;
    __syncthreads();
    for (int s = 128; s > 0; s >>= 1) {
        if (t < s) red[t] += red[t + s];
        __syncthreads();
    }
    if (t == 0) atomicAdd(lossAcc, red[0]);
}

// ---------------- finalize loss ----------------
__global__ void k_loss(const float* __restrict__ lossAcc, float* __restrict__ outLoss) {
    if (threadIdx.x == 0) {
        float m = lossAcc[0] * (1.0f / 4194304.0f);
        outLoss[0] = m + 0.25f * m;
    }
}

extern "C" void kernel_launch(void* const* d_in, const int* in_sizes, int n_in,
                              void* d_out, int out_size, void* d_ws, size_t ws_size,
                              hipStream_t stream) {
    const float* z   = (const float*)d_in[0];
    const float* emb = (const float*)d_in[1];
    float* outf = (float*)d_out;
    float* wsf  = (float*)d_ws;

    float* lossAcc = wsf;
    float* znorm   = wsf + WS_ZNORM;
    float* enorm   = wsf + WS_ENORM;
    int*   candCnt = (int*)(wsf + WS_CCNT);
    int*   candI   = (int*)(wsf + WS_CIDX);

    // d_out z_q region doubles as scratch: bf16 zb16/ebf until k_cand completes,
    // then fp32 z_t until k_gather overwrites it with z_q.
    unsigned short* zb16 = (unsigned short*)outf;                  // 8 MB
    unsigned short* ebf  = (unsigned short*)(outf + 2097152);      // 4 MB
    float* zt = outf;                                              // 16 MB (after k_cand)

    k_prep_z<<<dim3(16, 4, 16), 256, 0, stream>>>(z, zb16);
    k_prep_e<<<1024, 256, 0, stream>>>(emb, ebf);
    k_znorm<<<64, 256, 0, stream>>>(z, znorm, lossAcc);
    k_enorm<<<2048, 256, 0, stream>>>(emb, enorm);
    k_cand<<<256, 512, 0, stream>>>(zb16, ebf, candCnt, candI);
    k_tr_z<<<dim3(16, 4, 16), 256, 0, stream>>>(z, zt);
    k_rescore2<<<4096, 256, 0, stream>>>(zt, emb, znorm, enorm, candCnt, candI, outf + Z_OUT);
    k_gather<<<512, 256, 0, stream>>>(z, emb, outf + Z_OUT, outf, lossAcc);
    k_loss<<<1, 64, 0, stream>>>(lossAcc, outf + Z_OUT + NPTS);
}

// Round 5
// 282.564 us; speedup vs baseline: 2.3809x; 1.0601x over previous
//
#include <hip/hip_runtime.h>
#include <math.h>

// Problem constants
#define NB   16
#define CC   256
#define NPTS 16384       // 16*32*32
#define KK   8192
#define Z_OUT 4194304    // NPTS*CC
// d_out: [0,Z_OUT) z_q_out (BCHW), [Z_OUT,Z_OUT+NPTS) idx as float, [Z_OUT+NPTS] loss
// d_out scratch reuse timeline:
//   before k_cand done: zb16 = bf16[16384][256] at slot 0, ebf = bf16[8192][256] at
//     slot 2,097,152
//   after  k_cand:      z_t  = f32 [16384][256] over [0, Z_OUT) (k_tr_z)
//   k_gather finally overwrites [0, Z_OUT) with z_q BCHW.

// ws layout (floats)
#define WS_ZNORM 64
#define WS_ENORM 16448
#define WS_CCNT  24640                // int[16384] candidate counts
#define WS_CIDX  41024                // int[16384][64] candidate k lists
#define CAND_CAP 64
#define LCAP     96                   // pre-filter per-n LDS list capacity
#define MARGIN   4.0e-4f              // > 2*eps_bf16 + d-quantum + enorm spread

typedef short v8s __attribute__((ext_vector_type(8)));
typedef float v4f __attribute__((ext_vector_type(4)));

__device__ __forceinline__ void gl_lds16(const void* g, void* l) {
    __builtin_amdgcn_global_load_lds((const __attribute__((address_space(1))) void*)g,
                                     (__attribute__((address_space(3))) void*)l, 16, 0, 0);
}
__device__ __forceinline__ unsigned short f2bf(float f) {   // RNE, finite inputs
    unsigned int u = __float_as_uint(f);
    return (unsigned short)((u + 0x7FFFu + ((u >> 16) & 1u)) >> 16);
}
// monotone float<->uint encoding for atomicMax on floats of any sign
__device__ __forceinline__ unsigned fenc(float f) {
    unsigned u = __float_as_uint(f);
    return (u & 0x80000000u) ? ~u : (u | 0x80000000u);
}
__device__ __forceinline__ float fdec(unsigned m) {
    unsigned u = (m & 0x80000000u) ? (m & 0x7fffffffu) : ~m;
    return __uint_as_float(u);
}

// ---------------- P0: z BCHW fp32 -> zb16[n][c] bf16 (transpose+cast) ----------------
__global__ void k_prep_z(const float* __restrict__ z, unsigned short* __restrict__ zb16) {
    __shared__ float ts[64][65];
    const int hw0 = blockIdx.x * 64, c0 = blockIdx.y * 64, b = blockIdx.z;
    const int tid = threadIdx.x;
#pragma unroll
    for (int p = 0; p < 4; ++p) {
        int u = p * 256 + tid;
        int ci = u >> 4, j4 = (u & 15) << 2;
        float4 v = *(const float4*)(z + (size_t)b * 262144 + (size_t)(c0 + ci) * 1024 + hw0 + j4);
        ts[ci][j4 + 0] = v.x; ts[ci][j4 + 1] = v.y; ts[ci][j4 + 2] = v.z; ts[ci][j4 + 3] = v.w;
    }
    __syncthreads();
#pragma unroll
    for (int p = 0; p < 4; ++p) {
        int u = p * 256 + tid;
        int hj = u >> 4, i4 = (u & 15) << 2;
        ushort4 o = make_ushort4(f2bf(ts[i4 + 0][hj]), f2bf(ts[i4 + 1][hj]),
                                 f2bf(ts[i4 + 2][hj]), f2bf(ts[i4 + 3][hj]));
        *(ushort4*)(zb16 + (size_t)(b * 1024 + hw0 + hj) * 256 + c0 + i4) = o;
    }
}

// ---------------- P0b: z BCHW fp32 -> z_t[n][c] fp32 (transpose, runs after k_cand) --
__global__ void k_tr_z(const float* __restrict__ z, float* __restrict__ zt) {
    __shared__ float ts[64][65];
    const int hw0 = blockIdx.x * 64, c0 = blockIdx.y * 64, b = blockIdx.z;
    const int tid = threadIdx.x;
#pragma unroll
    for (int p = 0; p < 4; ++p) {
        int u = p * 256 + tid;
        int ci = u >> 4, j4 = (u & 15) << 2;
        float4 v = *(const float4*)(z + (size_t)b * 262144 + (size_t)(c0 + ci) * 1024 + hw0 + j4);
        ts[ci][j4 + 0] = v.x; ts[ci][j4 + 1] = v.y; ts[ci][j4 + 2] = v.z; ts[ci][j4 + 3] = v.w;
    }
    __syncthreads();
#pragma unroll
    for (int p = 0; p < 4; ++p) {
        int u = p * 256 + tid;
        int hj = u >> 4, i4 = (u & 15) << 2;
        float4 o = make_float4(ts[i4 + 0][hj], ts[i4 + 1][hj], ts[i4 + 2][hj], ts[i4 + 3][hj]);
        *(float4*)(zt + (size_t)(b * 1024 + hw0 + hj) * 256 + c0 + i4) = o;
    }
}

// ---------------- P1: emb fp32 -> ebf[k][c] bf16 ----------------
__global__ void k_prep_e(const float* __restrict__ emb, unsigned short* __restrict__ ebf) {
    const int i = (blockIdx.x * 256 + threadIdx.x) * 8;
    float4 a = *(const float4*)(emb + i);
    float4 b = *(const float4*)(emb + i + 4);
    *(ushort4*)(ebf + i)     = make_ushort4(f2bf(a.x), f2bf(a.y), f2bf(a.z), f2bf(a.w));
    *(ushort4*)(ebf + i + 4) = make_ushort4(f2bf(b.x), f2bf(b.y), f2bf(b.z), f2bf(b.w));
}

// ---------------- znorm + zero loss ----------------
__global__ void k_znorm(const float* __restrict__ z, float* __restrict__ znorm,
                        float* __restrict__ lossAcc) {
    const int n  = blockIdx.x * 256 + threadIdx.x;
    const int b  = n >> 10, hw = n & 1023;
    const float* p = z + (size_t)b * 262144 + hw;
    float s = 0.0f;
#pragma unroll 8
    for (int c = 0; c < CC; ++c) {
        float v = p[(size_t)c * 1024];
        s = fmaf(v, v, s);
    }
    znorm[n] = s;
    if (n == 0) lossAcc[0] = 0.0f;
}

// ---------------- enorm ----------------
__global__ void k_enorm(const float* __restrict__ emb, float* __restrict__ enorm) {
    const int w = threadIdx.x >> 6, lane = threadIdx.x & 63;
    const int k = blockIdx.x * 4 + w;
    float4 v = *(const float4*)(emb + (size_t)k * CC + lane * 4);
    float s = v.x * v.x + v.y * v.y + v.z * v.z + v.w * v.w;
    for (int off = 32; off > 0; off >>= 1) s += __shfl_down(s, off);
    if (lane == 0) enorm[k] = s;
}

// ---------------- Phase 1: single-sweep MFMA candidate generation -------------------
// 256 blocks x 1024 thr (16 waves, 4 waves/SIMD), block = 64 n (B z-tile staged ONCE
// in LDS, 32 KB, shared by all 16 waves), wave w owns k in [w*512,(w+1)*512):
// 8 chunks of 64 k, full c=256 per chunk. A (e-rows, L2/L3-resident) loaded straight
// to registers. k-loop is barrier-free except one staleness-bounding __syncthreads
// at mid-sweep (s==3).
// Progressive threshold per chunk = max(shared LDS runmax, OWN chunk max in-register)
// - MARGIN: the own-chunk term makes the push condition robust to LDS staleness
// (pushed set is always a superset of the final-margin set, since both terms are
// <= the true global max). (k, dot) pairs pushed to LDS lists (cap LCAP).
// Epilogue: block covers full k -> runmaxU is the TRUE global bf16 max per n; filter
// stored dots vs finalmax-MARGIN -> candCnt is the exact margin-window count (~2-5).
// Overflow anywhere -> candCnt=KK -> rescore exact full-scan fallback.
// Register budget note (rounds 2/3 lesson): 4 waves/SIMD requires VGPR<=128; this
// inner loop compiled to 88 VGPR in round 4 -> ~40 regs headroom, no spill expected.
// mfma_f32_16x16x32_bf16: A[m=lane&15][c=(lane>>4)*8+j]; B[c][n=lane&15];
// D: col(n)=lane&15, row(k)=(lane>>4)*4+reg.
__global__ __launch_bounds__(1024, 4)
void k_cand(const unsigned short* __restrict__ zb16, const unsigned short* __restrict__ ebf,
            int* __restrict__ candCnt, int* __restrict__ candI) {
    __shared__ short    Bs[8][4][512];      // 32 KB  [cchunk][ntile][lane*8]
    __shared__ unsigned runmaxU[64];        // ordered-uint running max per n
    __shared__ int      cnt[64];
    __shared__ int      lstK[64][LCAP];     // 24 KB
    __shared__ float    lstD[64][LCAP];     // 24 KB

    const int tid  = threadIdx.x;
    const int lane = tid & 63;
    const int w    = tid >> 6;              // 0..15
    const int nb   = blockIdx.x << 6;
    const int m16  = lane & 15, q = lane >> 4;

    if (tid < 64) { runmaxU[tid] = 0x007FFFFFu; /* fenc(-inf) */ cnt[tid] = 0; }

    // stage B-tile once: 32 (cc,nt) fragments x 64 lanes x 16B; 2 per wave
#pragma unroll
    for (int p = 0; p < 2; ++p) {
        const int g8 = p * 16 + w;         // 0..31, wave-uniform
        const int cc = g8 >> 2, nt = g8 & 3;
        const unsigned short* g = zb16 + (size_t)(nb + nt * 16 + m16) * 256 + cc * 32 + q * 8;
        gl_lds16(g, &Bs[cc][nt][lane * 8]);
    }
    __syncthreads();       // Bs + runmaxU/cnt init visible (barrier drains vmcnt)

    int kb = w << 9;       // wave's 512-k range, 8 chunks of 64
#pragma unroll 1
    for (int s = 0; s < 8; ++s) {
        v4f acc[16];
#pragma unroll
        for (int i = 0; i < 16; ++i) acc[i] = (v4f){0.f, 0.f, 0.f, 0.f};

#pragma unroll
        for (int cc = 0; cc < 8; ++cc) {
            v8s a[4], bfg[4];
#pragma unroll
            for (int kt = 0; kt < 4; ++kt)
                a[kt] = *(const v8s*)(ebf + (size_t)(kb + (kt << 4) + m16) * 256 + (cc << 5) + q * 8);
#pragma unroll
            for (int nt = 0; nt < 4; ++nt) bfg[nt] = *(const v8s*)&Bs[cc][nt][lane * 8];
#pragma unroll
            for (int kt = 0; kt < 4; ++kt)
#pragma unroll
                for (int nt = 0; nt < 4; ++nt)
                    acc[kt * 4 + nt] = __builtin_amdgcn_mfma_f32_16x16x32_bf16(
                        a[kt], bfg[nt], acc[kt * 4 + nt], 0, 0, 0);
        }

        // chunk epilogue: own-chunk max per n-column (all lanes end up holding the max
        // for their m16 column), merge into shared runmax, then push with robust thr.
        float mx[4];
#pragma unroll
        for (int nt = 0; nt < 4; ++nt) {
            float m = acc[0 * 4 + nt][0];
#pragma unroll
            for (int kt = 0; kt < 4; ++kt)
#pragma unroll
                for (int r = 0; r < 4; ++r) m = fmaxf(m, acc[kt * 4 + nt][r]);
            m = fmaxf(m, __shfl_xor(m, 16));
            m = fmaxf(m, __shfl_xor(m, 32));
            mx[nt] = m;                     // all lanes: chunk max of column n=nt*16+m16
            if (lane < 16) atomicMax(&runmaxU[nt * 16 + lane], fenc(m));
        }
#pragma unroll
        for (int nt = 0; nt < 4; ++nt) {
            const int nl = nt * 16 + m16;
            const float thr = fmaxf(fdec(runmaxU[nl]), mx[nt]) - MARGIN;
#pragma unroll
            for (int kt = 0; kt < 4; ++kt)
#pragma unroll
                for (int r = 0; r < 4; ++r) {
                    if (acc[kt * 4 + nt][r] >= thr) {
                        int k = kb + (kt << 4) + q * 4 + r;
                        int pos = atomicAdd(&cnt[nl], 1);
                        if (pos < LCAP) { lstK[nl][pos] = k; lstD[nl][pos] = acc[kt * 4 + nt][r]; }
                    }
                }
        }
        kb += 64;
        if (s == 3) __syncthreads();       // bound cross-wave staleness mid-sweep
    }

    __syncthreads();   // all pushes + atomicMax done; runmaxU now TRUE global max per n
    if (tid < 64) {
        const int n = nb + tid;
        const int c = cnt[tid];
        if (c > LCAP) {
            candCnt[n] = KK;               // overflow -> exact full-scan fallback
        } else {
            const float thr = fdec(runmaxU[tid]) - MARGIN;
            int kept = 0;
            for (int i = 0; i < c; ++i) {
                if (lstD[tid][i] >= thr) {
                    if (kept < CAND_CAP) candI[(size_t)n * CAND_CAP + kept] = lstK[tid][i];
                    ++kept;
                }
            }
            candCnt[n] = (kept > CAND_CAP) ? KK : kept;
        }
    }
}

// ---------------- Phase 2: exact fp32 rescore, wave-per-n, lane-parallel dot ----------
// One wave owns one n. Lane l holds z_t[n][4l..4l+3] (coalesced 1 KB row load).
// Per candidate: coalesced emb-row load, 4 fmaf + 6-step butterfly -> uniform dot.
// d = (zn + enorm[k]) - (p + p); ties -> smallest k (order-invariant selection).
__global__ __launch_bounds__(256)
void k_rescore2(const float* __restrict__ zt, const float* __restrict__ emb,
                const float* __restrict__ znorm, const float* __restrict__ enorm,
                const int* __restrict__ candCnt, const int* __restrict__ candI,
                float* __restrict__ idx_out) {
    const int lane = threadIdx.x & 63;
    const int n    = blockIdx.x * 4 + (threadIdx.x >> 6);
    const float zn = znorm[n];
    const int  cnt = candCnt[n];
    const float4 zv = *(const float4*)(zt + (size_t)n * CC + lane * 4);
    float bd = __builtin_inff();
    int   bk = 0x7fffffff;
    if (cnt <= CAND_CAP) {
#pragma unroll 1
        for (int i = 0; i < cnt; ++i) {
            const int k = candI[(size_t)n * CAND_CAP + i];
            const float4 ev = *(const float4*)(emb + (size_t)k * CC + lane * 4);
            float p = zv.x * ev.x;
            p = fmaf(zv.y, ev.y, p);
            p = fmaf(zv.z, ev.z, p);
            p = fmaf(zv.w, ev.w, p);
#pragma unroll
            for (int off = 1; off < 64; off <<= 1) p += __shfl_xor(p, off);
            const float d = (zn + enorm[k]) - (p + p);
            if (d < bd || (d == bd && k < bk)) { bd = d; bk = k; }
        }
    } else {
        // overflow fallback: exact full scan, all lanes active, ascending k keeps min-k
#pragma unroll 1
        for (int k = 0; k < KK; ++k) {
            const float4 ev = *(const float4*)(emb + (size_t)k * CC + lane * 4);
            float p = zv.x * ev.x;
            p = fmaf(zv.y, ev.y, p);
            p = fmaf(zv.z, ev.z, p);
            p = fmaf(zv.w, ev.w, p);
#pragma unroll
            for (int off = 1; off < 64; off <<= 1) p += __shfl_xor(p, off);
            const float d = (zn + enorm[k]) - (p + p);
            if (d < bd) { bd = d; bk = k; }
        }
    }
    if (lane == 0) idx_out[n] = (float)bk;
}

// ---------------- gather z_q (BCHW) + loss partials ----------------
__global__ void k_gather(const float* __restrict__ z, const float* __restrict__ emb,
                         const float* __restrict__ idxf, float* __restrict__ out,
                         float* __restrict__ lossAcc) {
    __shared__ float red[256];
    const int bid = blockIdx.x;
    const int b = bid >> 5, h = bid & 31;
    const int t = threadIdx.x;
    const int w_ = t & 31, cg = t >> 5;
    const int n = b * 1024 + h * 32 + w_;
    const int ki = (int)idxf[n];
    const float* ep = emb + (size_t)ki * CC;
    const size_t base = (size_t)b * 262144 + h * 32 + w_;
    float ls = 0.0f;
#pragma unroll 4
    for (int c = cg; c < CC; c += 8) {
        float e = ep[c];
        size_t a = base + (size_t)c * 1024;
        float zv = z[a];
        out[a] = e;
        float df = e - zv;
        ls = fmaf(df, df, ls);
    }
    red[t] = ls;
    __syncthreads();
    for (int s = 128; s > 0; s >>= 1) {
        if (t < s) red[t] += red[t + s];
        __syncthreads();
    }
    if (t == 0) atomicAdd(lossAcc, red[0]);
}

// ---------------- finalize loss ----------------
__global__ void k_loss(const float* __restrict__ lossAcc, float* __restrict__ outLoss) {
    if (threadIdx.x == 0) {
        float m = lossAcc[0] * (1.0f / 4194304.0f);
        outLoss[0] = m + 0.25f * m;
    }
}

extern "C" void kernel_launch(void* const* d_in, const int* in_sizes, int n_in,
                              void* d_out, int out_size, void* d_ws, size_t ws_size,
                              hipStream_t stream) {
    const float* z   = (const float*)d_in[0];
    const float* emb = (const float*)d_in[1];
    float* outf = (float*)d_out;
    float* wsf  = (float*)d_ws;

    float* lossAcc = wsf;
    float* znorm   = wsf + WS_ZNORM;
    float* enorm   = wsf + WS_ENORM;
    int*   candCnt = (int*)(wsf + WS_CCNT);
    int*   candI   = (int*)(wsf + WS_CIDX);

    // d_out z_q region doubles as scratch: bf16 zb16/ebf until k_cand completes,
    // then fp32 z_t until k_gather overwrites it with z_q.
    unsigned short* zb16 = (unsigned short*)outf;                  // 8 MB
    unsigned short* ebf  = (unsigned short*)(outf + 2097152);      // 4 MB
    float* zt = outf;                                              // 16 MB (after k_cand)

    k_prep_z<<<dim3(16, 4, 16), 256, 0, stream>>>(z, zb16);
    k_prep_e<<<1024, 256, 0, stream>>>(emb, ebf);
    k_znorm<<<64, 256, 0, stream>>>(z, znorm, lossAcc);
    k_enorm<<<2048, 256, 0, stream>>>(emb, enorm);
    k_cand<<<256, 1024, 0, stream>>>(zb16, ebf, candCnt, candI);
    k_tr_z<<<dim3(16, 4, 16), 256, 0, stream>>>(z, zt);
    k_rescore2<<<4096, 256, 0, stream>>>(zt, emb, znorm, enorm, candCnt, candI, outf + Z_OUT);
    k_gather<<<512, 256, 0, stream>>>(z, emb, outf + Z_OUT, outf, lossAcc);
    k_loss<<<1, 64, 0, stream>>>(lossAcc, outf + Z_OUT + NPTS);
}

// Round 6
// 278.423 us; speedup vs baseline: 2.4163x; 1.0149x over previous
//
#include <hip/hip_runtime.h>
#include <math.h>

// Problem constants
#define NB   16
#define CC   256
#define NPTS 16384       // 16*32*32
#define KK   8192
#define Z_OUT 4194304    // NPTS*CC
// d_out: [0,Z_OUT) z_q_out (BCHW), [Z_OUT,Z_OUT+NPTS) idx as float, [Z_OUT+NPTS] loss
// d_out scratch reuse timeline:
//   before k_cand done: zb16 = bf16[16384][256] at slot 0, ebf = bf16[8192][256] at
//     slot 2,097,152
//   after  k_cand:      z_t  = f32 [16384][256] over [0, Z_OUT) (k_tr_z)
//   k_gather finally overwrites [0, Z_OUT) with z_q BCHW.

// ws layout (floats)
#define WS_ZNORM 64
#define WS_ENORM 16448
#define WS_CCNT  24640                // int[16384] candidate counts
#define WS_CIDX  41024                // int[16384][64] candidate k lists
#define CAND_CAP 64
#define LCAP     96                   // pre-filter per-n LDS list capacity
#define MARGIN   4.0e-4f              // > 2*eps_bf16 + d-quantum + enorm spread

typedef short v8s __attribute__((ext_vector_type(8)));
typedef float v4f __attribute__((ext_vector_type(4)));

__device__ __forceinline__ void gl_lds16(const void* g, void* l) {
    __builtin_amdgcn_global_load_lds((const __attribute__((address_space(1))) void*)g,
                                     (__attribute__((address_space(3))) void*)l, 16, 0, 0);
}
__device__ __forceinline__ unsigned short f2bf(float f) {   // RNE, finite inputs
    unsigned int u = __float_as_uint(f);
    return (unsigned short)((u + 0x7FFFu + ((u >> 16) & 1u)) >> 16);
}
// monotone float<->uint encoding for atomicMax on floats of any sign
__device__ __forceinline__ unsigned fenc(float f) {
    unsigned u = __float_as_uint(f);
    return (u & 0x80000000u) ? ~u : (u | 0x80000000u);
}
__device__ __forceinline__ float fdec(unsigned m) {
    unsigned u = (m & 0x80000000u) ? (m & 0x7fffffffu) : ~m;
    return __uint_as_float(u);
}

// ---------------- P0: z BCHW fp32 -> zb16[n][c] bf16 (transpose+cast) ----------------
__global__ void k_prep_z(const float* __restrict__ z, unsigned short* __restrict__ zb16) {
    __shared__ float ts[64][65];
    const int hw0 = blockIdx.x * 64, c0 = blockIdx.y * 64, b = blockIdx.z;
    const int tid = threadIdx.x;
#pragma unroll
    for (int p = 0; p < 4; ++p) {
        int u = p * 256 + tid;
        int ci = u >> 4, j4 = (u & 15) << 2;
        float4 v = *(const float4*)(z + (size_t)b * 262144 + (size_t)(c0 + ci) * 1024 + hw0 + j4);
        ts[ci][j4 + 0] = v.x; ts[ci][j4 + 1] = v.y; ts[ci][j4 + 2] = v.z; ts[ci][j4 + 3] = v.w;
    }
    __syncthreads();
#pragma unroll
    for (int p = 0; p < 4; ++p) {
        int u = p * 256 + tid;
        int hj = u >> 4, i4 = (u & 15) << 2;
        ushort4 o = make_ushort4(f2bf(ts[i4 + 0][hj]), f2bf(ts[i4 + 1][hj]),
                                 f2bf(ts[i4 + 2][hj]), f2bf(ts[i4 + 3][hj]));
        *(ushort4*)(zb16 + (size_t)(b * 1024 + hw0 + hj) * 256 + c0 + i4) = o;
    }
}

// ---------------- P0b: z BCHW fp32 -> z_t[n][c] fp32 (transpose, runs after k_cand) --
__global__ void k_tr_z(const float* __restrict__ z, float* __restrict__ zt) {
    __shared__ float ts[64][65];
    const int hw0 = blockIdx.x * 64, c0 = blockIdx.y * 64, b = blockIdx.z;
    const int tid = threadIdx.x;
#pragma unroll
    for (int p = 0; p < 4; ++p) {
        int u = p * 256 + tid;
        int ci = u >> 4, j4 = (u & 15) << 2;
        float4 v = *(const float4*)(z + (size_t)b * 262144 + (size_t)(c0 + ci) * 1024 + hw0 + j4);
        ts[ci][j4 + 0] = v.x; ts[ci][j4 + 1] = v.y; ts[ci][j4 + 2] = v.z; ts[ci][j4 + 3] = v.w;
    }
    __syncthreads();
#pragma unroll
    for (int p = 0; p < 4; ++p) {
        int u = p * 256 + tid;
        int hj = u >> 4, i4 = (u & 15) << 2;
        float4 o = make_float4(ts[i4 + 0][hj], ts[i4 + 1][hj], ts[i4 + 2][hj], ts[i4 + 3][hj]);
        *(float4*)(zt + (size_t)(b * 1024 + hw0 + hj) * 256 + c0 + i4) = o;
    }
}

// ---------------- P1: emb fp32 -> ebf[k][c] bf16, fused with enorm ----------------
// 2048 blocks x 256 thr: 4 rows/block, 1 wave/row; lane holds float4 of the row.
__global__ void k_prep_e(const float* __restrict__ emb, unsigned short* __restrict__ ebf,
                         float* __restrict__ enorm) {
    const int w = threadIdx.x >> 6, lane = threadIdx.x & 63;
    const int k = blockIdx.x * 4 + w;
    const int i = k * CC + lane * 4;
    float4 v = *(const float4*)(emb + i);
    *(ushort4*)(ebf + i) = make_ushort4(f2bf(v.x), f2bf(v.y), f2bf(v.z), f2bf(v.w));
    float s = v.x * v.x + v.y * v.y + v.z * v.z + v.w * v.w;
    for (int off = 32; off > 0; off >>= 1) s += __shfl_down(s, off);
    if (lane == 0) enorm[k] = s;
}

// ---------------- znorm + zero loss ----------------
__global__ void k_znorm(const float* __restrict__ z, float* __restrict__ znorm,
                        float* __restrict__ lossAcc) {
    const int n  = blockIdx.x * 256 + threadIdx.x;
    const int b  = n >> 10, hw = n & 1023;
    const float* p = z + (size_t)b * 262144 + hw;
    float s = 0.0f;
#pragma unroll 8
    for (int c = 0; c < CC; ++c) {
        float v = p[(size_t)c * 1024];
        s = fmaf(v, v, s);
    }
    znorm[n] = s;
    if (n == 0) lossAcc[0] = 0.0f;
}

// ---------------- Phase 1: single-sweep MFMA candidate generation -------------------
// 256 blocks x 512 thr (8 waves, 2 waves/SIMD -> 256-reg budget, the proven-safe
// point). Block = 64 n (B z-tile staged ONCE in LDS, 32 KB, shared by all waves).
// STRIDED chunk schedule (L2-locality fix): wave w processes chunk ci = s*8 + w,
// k in [ci*64, ci*64+64). At any instant the 8 waves -- and all blocks on an XCD --
// sweep the SAME ~512 KB window of ebf, so e-rows hit in L2 instead of thrashing
// the 4 MB L2 with the whole 4 MB table (round-5 behavior: wave w started at w*512,
// block working set = entire ebf = L2 size -> L3-latency-bound, MfmaUtil 18%).
// A (e-rows) + B (LDS) fragments manually ping-pong prefetched one cc-step ahead
// (round-2 inner-loop pattern; reg budget 64 AGPR acc + ~32 A + ~32 B + misc < 256).
// Progressive threshold per chunk = max(shared LDS runmax, OWN chunk max) - MARGIN:
// own-chunk term makes pushes robust to LDS staleness (always a superset of the
// final-margin set). (k, dot) pairs pushed to LDS lists (cap LCAP).
// Epilogue: block covers full k -> runmaxU is the TRUE global bf16 max per n; filter
// stored dots vs finalmax-MARGIN -> candCnt exact margin-window count (~2-5).
// Overflow anywhere -> candCnt=KK -> rescore exact full-scan fallback.
// mfma_f32_16x16x32_bf16: A[m=lane&15][c=(lane>>4)*8+j]; B[c][n=lane&15];
// D: col(n)=lane&15, row(k)=(lane>>4)*4+reg.
__global__ __launch_bounds__(512, 2)
void k_cand(const unsigned short* __restrict__ zb16, const unsigned short* __restrict__ ebf,
            int* __restrict__ candCnt, int* __restrict__ candI) {
    __shared__ short    Bs[8][4][512];      // 32 KB  [cchunk][ntile][lane*8]
    __shared__ unsigned runmaxU[64];        // ordered-uint running max per n
    __shared__ int      cnt[64];
    __shared__ int      lstK[64][LCAP];     // 24 KB
    __shared__ float    lstD[64][LCAP];     // 24 KB

    const int tid  = threadIdx.x;
    const int lane = tid & 63;
    const int w    = tid >> 6;              // 0..7
    const int nb   = blockIdx.x << 6;
    const int m16  = lane & 15, q = lane >> 4;

    if (tid < 64) { runmaxU[tid] = 0x007FFFFFu; /* fenc(-inf) */ cnt[tid] = 0; }

    // stage B-tile once: 32 (cc,nt) fragments x 64 lanes x 16B; 4 per wave
#pragma unroll
    for (int p = 0; p < 4; ++p) {
        const int g8 = p * 8 + w;          // 0..31, wave-uniform
        const int cc = g8 >> 2, nt = g8 & 3;
        const unsigned short* g = zb16 + (size_t)(nb + nt * 16 + m16) * 256 + cc * 32 + q * 8;
        gl_lds16(g, &Bs[cc][nt][lane * 8]);
    }

    auto loadA = [&](v8s (&a)[4], int kbr, int cc) {
#pragma unroll
        for (int kt = 0; kt < 4; ++kt)
            a[kt] = *(const v8s*)(ebf + (size_t)(kbr + (kt << 4) + m16) * 256 + (cc << 5) + q * 8);
    };
    auto loadB = [&](v8s (&b)[4], int cc) {
#pragma unroll
        for (int nt = 0; nt < 4; ++nt) b[nt] = *(const v8s*)&Bs[cc][nt][lane * 8];
    };

    v8s aP[4], aN[4], bP[4], bN[4];
    loadA(aP, w << 6, 0);          // registers only; safe before the staging barrier
    __syncthreads();               // Bs + runmaxU/cnt init visible (drains vmcnt)
    loadB(bP, 0);

#pragma unroll 1
    for (int s = 0; s < 16; ++s) {
        const int kb  = (s * 8 + w) << 6;                    // this wave's chunk
        const int kbn = (s < 15) ? kb + 512 : kb;            // next chunk (clamped)
        v4f acc[16];
#pragma unroll
        for (int i = 0; i < 16; ++i) acc[i] = (v4f){0.f, 0.f, 0.f, 0.f};

#pragma unroll
        for (int cc = 0; cc < 8; ++cc) {
            if ((cc & 1) == 0) {
                // consuming aP/bP; prefetch cc+1 into aN/bN
                loadA(aN, kb, cc + 1);
                loadB(bN, cc + 1);
#pragma unroll
                for (int kt = 0; kt < 4; ++kt)
#pragma unroll
                    for (int nt = 0; nt < 4; ++nt)
                        acc[kt * 4 + nt] = __builtin_amdgcn_mfma_f32_16x16x32_bf16(
                            aP[kt], bP[nt], acc[kt * 4 + nt], 0, 0, 0);
            } else {
                // consuming aN/bN; prefetch cc+1 (or next-s cc0) into aP/bP
                if (cc < 7) { loadA(aP, kb, cc + 1);  loadB(bP, cc + 1); }
                else        { loadA(aP, kbn, 0);      loadB(bP, 0);      }
#pragma unroll
                for (int kt = 0; kt < 4; ++kt)
#pragma unroll
                    for (int nt = 0; nt < 4; ++nt)
                        acc[kt * 4 + nt] = __builtin_amdgcn_mfma_f32_16x16x32_bf16(
                            aN[kt], bN[nt], acc[kt * 4 + nt], 0, 0, 0);
            }
        }

        // chunk epilogue: own-chunk max per n-column, merge into shared runmax, push.
        float mx[4];
#pragma unroll
        for (int nt = 0; nt < 4; ++nt) {
            float m = acc[0 * 4 + nt][0];
#pragma unroll
            for (int kt = 0; kt < 4; ++kt)
#pragma unroll
                for (int r = 0; r < 4; ++r) m = fmaxf(m, acc[kt * 4 + nt][r]);
            m = fmaxf(m, __shfl_xor(m, 16));
            m = fmaxf(m, __shfl_xor(m, 32));
            mx[nt] = m;                     // all lanes: chunk max of column n=nt*16+m16
            if (lane < 16) atomicMax(&runmaxU[nt * 16 + lane], fenc(m));
        }
#pragma unroll
        for (int nt = 0; nt < 4; ++nt) {
            const int nl = nt * 16 + m16;
            const float thr = fmaxf(fdec(runmaxU[nl]), mx[nt]) - MARGIN;
#pragma unroll
            for (int kt = 0; kt < 4; ++kt)
#pragma unroll
                for (int r = 0; r < 4; ++r) {
                    if (acc[kt * 4 + nt][r] >= thr) {
                        int k = kb + (kt << 4) + q * 4 + r;
                        int pos = atomicAdd(&cnt[nl], 1);
                        if (pos < LCAP) { lstK[nl][pos] = k; lstD[nl][pos] = acc[kt * 4 + nt][r]; }
                    }
                }
        }
        if (s == 3 || s == 9) __syncthreads();   // bound cross-wave staleness
    }

    __syncthreads();   // all pushes + atomicMax done; runmaxU now TRUE global max per n
    if (tid < 64) {
        const int n = nb + tid;
        const int c = cnt[tid];
        if (c > LCAP) {
            candCnt[n] = KK;               // overflow -> exact full-scan fallback
        } else {
            const float thr = fdec(runmaxU[tid]) - MARGIN;
            int kept = 0;
            for (int i = 0; i < c; ++i) {
                if (lstD[tid][i] >= thr) {
                    if (kept < CAND_CAP) candI[(size_t)n * CAND_CAP + kept] = lstK[tid][i];
                    ++kept;
                }
            }
            candCnt[n] = (kept > CAND_CAP) ? KK : kept;
        }
    }
}

// ---------------- Phase 2: exact fp32 rescore, wave-per-n, lane-parallel dot ----------
// One wave owns one n. Lane l holds z_t[n][4l..4l+3] (coalesced 1 KB row load).
// Per candidate: coalesced emb-row load, 4 fmaf + 6-step butterfly -> uniform dot.
// d = (zn + enorm[k]) - (p + p); ties -> smallest k (order-invariant selection).
__global__ __launch_bounds__(256)
void k_rescore2(const float* __restrict__ zt, const float* __restrict__ emb,
                const float* __restrict__ znorm, const float* __restrict__ enorm,
                const int* __restrict__ candCnt, const int* __restrict__ candI,
                float* __restrict__ idx_out) {
    const int lane = threadIdx.x & 63;
    const int n    = blockIdx.x * 4 + (threadIdx.x >> 6);
    const float zn = znorm[n];
    const int  cnt = candCnt[n];
    const float4 zv = *(const float4*)(zt + (size_t)n * CC + lane * 4);
    float bd = __builtin_inff();
    int   bk = 0x7fffffff;
    if (cnt <= CAND_CAP) {
#pragma unroll 1
        for (int i = 0; i < cnt; ++i) {
            const int k = candI[(size_t)n * CAND_CAP + i];
            const float4 ev = *(const float4*)(emb + (size_t)k * CC + lane * 4);
            float p = zv.x * ev.x;
            p = fmaf(zv.y, ev.y, p);
            p = fmaf(zv.z, ev.z, p);
            p = fmaf(zv.w, ev.w, p);
#pragma unroll
            for (int off = 1; off < 64; off <<= 1) p += __shfl_xor(p, off);
            const float d = (zn + enorm[k]) - (p + p);
            if (d < bd || (d == bd && k < bk)) { bd = d; bk = k; }
        }
    } else {
        // overflow fallback: exact full scan, all lanes active, ascending k keeps min-k
#pragma unroll 1
        for (int k = 0; k < KK; ++k) {
            const float4 ev = *(const float4*)(emb + (size_t)k * CC + lane * 4);
            float p = zv.x * ev.x;
            p = fmaf(zv.y, ev.y, p);
            p = fmaf(zv.z, ev.z, p);
            p = fmaf(zv.w, ev.w, p);
#pragma unroll
            for (int off = 1; off < 64; off <<= 1) p += __shfl_xor(p, off);
            const float d = (zn + enorm[k]) - (p + p);
            if (d < bd) { bd = d; bk = k; }
        }
    }
    if (lane == 0) idx_out[n] = (float)bk;
}

// ---------------- gather z_q (BCHW) + loss partials ----------------
__global__ void k_gather(const float* __restrict__ z, const float* __restrict__ emb,
                         const float* __restrict__ idxf, float* __restrict__ out,
                         float* __restrict__ lossAcc) {
    __shared__ float red[256];
    const int bid = blockIdx.x;
    const int b = bid >> 5, h = bid & 31;
    const int t = threadIdx.x;
    const int w_ = t & 31, cg = t >> 5;
    const int n = b * 1024 + h * 32 + w_;
    const int ki = (int)idxf[n];
    const float* ep = emb + (size_t)ki * CC;
    const size_t base = (size_t)b * 262144 + h * 32 + w_;
    float ls = 0.0f;
#pragma unroll 4
    for (int c = cg; c < CC; c += 8) {
        float e = ep[c];
        size_t a = base + (size_t)c * 1024;
        float zv = z[a];
        out[a] = e;
        float df = e - zv;
        ls = fmaf(df, df, ls);
    }
    red[t] = ls;
    __syncthreads();
    for (int s = 128; s > 0; s >>= 1) {
        if (t < s) red[t] += red[t + s];
        __syncthreads();
    }
    if (t == 0) atomicAdd(lossAcc, red[0]);
}

// ---------------- finalize loss ----------------
__global__ void k_loss(const float* __restrict__ lossAcc, float* __restrict__ outLoss) {
    if (threadIdx.x == 0) {
        float m = lossAcc[0] * (1.0f / 4194304.0f);
        outLoss[0] = m + 0.25f * m;
    }
}

extern "C" void kernel_launch(void* const* d_in, const int* in_sizes, int n_in,
                              void* d_out, int out_size, void* d_ws, size_t ws_size,
                              hipStream_t stream) {
    const float* z   = (const float*)d_in[0];
    const float* emb = (const float*)d_in[1];
    float* outf = (float*)d_out;
    float* wsf  = (float*)d_ws;

    float* lossAcc = wsf;
    float* znorm   = wsf + WS_ZNORM;
    float* enorm   = wsf + WS_ENORM;
    int*   candCnt = (int*)(wsf + WS_CCNT);
    int*   candI   = (int*)(wsf + WS_CIDX);

    // d_out z_q region doubles as scratch: bf16 zb16/ebf until k_cand completes,
    // then fp32 z_t until k_gather overwrites it with z_q.
    unsigned short* zb16 = (unsigned short*)outf;                  // 8 MB
    unsigned short* ebf  = (unsigned short*)(outf + 2097152);      // 4 MB
    float* zt = outf;                                              // 16 MB (after k_cand)

    k_prep_z<<<dim3(16, 4, 16), 256, 0, stream>>>(z, zb16);
    k_prep_e<<<2048, 256, 0, stream>>>(emb, ebf, enorm);
    k_znorm<<<64, 256, 0, stream>>>(z, znorm, lossAcc);
    k_cand<<<256, 512, 0, stream>>>(zb16, ebf, candCnt, candI);
    k_tr_z<<<dim3(16, 4, 16), 256, 0, stream>>>(z, zt);
    k_rescore2<<<4096, 256, 0, stream>>>(zt, emb, znorm, enorm, candCnt, candI, outf + Z_OUT);
    k_gather<<<512, 256, 0, stream>>>(z, emb, outf + Z_OUT, outf, lossAcc);
    k_loss<<<1, 64, 0, stream>>>(lossAcc, outf + Z_OUT + NPTS);
}